// Round 8
// baseline (488.925 us; speedup 1.0000x reference)
//
#include <hip/hip_runtime.h>
#include <math.h>

// BasicRecurrentEntityEncoder: B=256, S=64, L=16, D=256, K=30
// Round 8 (= round-7 resubmit; r7 bench was an infra acquisition timeout):
// round-6 + (a) B planes PINNED in VGPRs via asm reg-barrier
// (r6 evidence: VGPR_Count=128 => compiler sank loadB into the loop,
// re-streaming 256KB/step from L2), (b) two independent MFMA acc chains.

constexpr int Sc = 64, Lc = 16, Dc = 256, Kc = 30;

typedef short s8v  __attribute__((ext_vector_type(8)));
typedef short s4v  __attribute__((ext_vector_type(4)));
typedef float f4v  __attribute__((ext_vector_type(4)));
typedef float f16v __attribute__((ext_vector_type(16)));

__device__ __forceinline__ short f2bf(float x) {  // RNE float->bf16
    unsigned u = __float_as_uint(x);
    u = u + 0x7FFFu + ((u >> 16) & 1u);
    return (short)(u >> 16);
}
__device__ __forceinline__ float bf2f(short s) {
    return __uint_as_float(((unsigned)(unsigned short)s) << 16);
}

// ---- wave-wide sum on the VALU pipe (DPP), result broadcast via SGPR ----
template <int CTRL, int RMASK>
__device__ __forceinline__ float dpp_add(float v) {
    int t = __builtin_amdgcn_update_dpp(0, __float_as_int(v), CTRL, RMASK, 0xF, true);
    return v + __int_as_float(t);
}
__device__ __forceinline__ float wave_sum(float v) {
    v = dpp_add<0x111, 0xF>(v);   // row_shr:1
    v = dpp_add<0x112, 0xF>(v);   // row_shr:2
    v = dpp_add<0x114, 0xF>(v);   // row_shr:4
    v = dpp_add<0x118, 0xF>(v);   // row_shr:8
    v = dpp_add<0x142, 0xA>(v);   // row_bcast15
    v = dpp_add<0x143, 0xC>(v);   // row_bcast31 ; lane63 = total
    return __int_as_float(__builtin_amdgcn_readlane(__float_as_int(v), 63));
}

// ---- pack U,V,W into bf16-split planes in 32x32x16 MFMA-B fragment order ----
// P[mat][plane][kt(16)][w(8)][lane(64)][elem(8)]
// logical k = 16*kt + 8*(l>>5) + elem ; logical n (col) = 32*w + (l&31)
__global__ void pack32(const float* __restrict__ U, const float* __restrict__ V,
                       const float* __restrict__ W, short* __restrict__ P) {
    int gid = blockIdx.x * blockDim.x + threadIdx.x;   // 3*16*8*64 = 24576
    int l = gid & 63, w = (gid >> 6) & 7, kt = (gid >> 9) & 15, mat = gid >> 13;
    const float* M = (mat == 0) ? U : ((mat == 1) ? V : W);
    short* P1 = P + (size_t)mat * 131072;
    short* P2 = P1 + 65536;
    int n  = 32 * w + (l & 31);
    int k0 = 16 * kt + 8 * (l >> 5);
    s8v hi, lo;
#pragma unroll
    for (int e = 0; e < 8; ++e) {
        float x = M[(size_t)(k0 + e) * Dc + n];
        short h = f2bf(x);
        hi[e] = h;
        lo[e] = f2bf(x - bf2f(h));
    }
    size_t idx = ((size_t)(kt * 8 + w) * 64 + l) * 8;
    *(s8v*)(P1 + idx) = hi;
    *(s8v*)(P2 + idx) = lo;
}

// swizzled LDS accessors
__device__ __forceinline__ int aoff(int row, int kbyte) { return (row * 512 + kbyte) ^ ((row & 31) << 4); }
__device__ __forceinline__ int coff(int row, int cbyte) { return (row * 1024 + cbyte) ^ ((row & 7) << 4); }

__device__ __forceinline__ void store_split_row(char* A1s, char* A2s, int row, int l,
                                                float x0, float x1, float x2, float x3) {
    s4v hi, lo;
    short h0 = f2bf(x0); hi[0] = h0; lo[0] = f2bf(x0 - bf2f(h0));
    short h1 = f2bf(x1); hi[1] = h1; lo[1] = f2bf(x1 - bf2f(h1));
    short h2 = f2bf(x2); hi[2] = h2; lo[2] = f2bf(x2 - bf2f(h2));
    short h3 = f2bf(x3); hi[3] = h3; lo[3] = f2bf(x3 - bf2f(h3));
    int off = aoff(row, 8 * l);
    *(s4v*)(A1s + off) = hi;
    *(s4v*)(A2s + off) = lo;
}

__device__ __forceinline__ void loadB(const short* __restrict__ P1, const short* __restrict__ P2,
                                      int w, int l, s8v (&b1)[16], s8v (&b2)[16]) {
#pragma unroll
    for (int kt = 0; kt < 16; ++kt) {
        size_t idx = ((size_t)(kt * 8 + w) * 64 + l) * 8;
        b1[kt] = *(const s8v*)(P1 + idx);
        b2[kt] = *(const s8v*)(P2 + idx);
    }
}

// force B planes to stay materialized in VGPRs (defeat load-sinking)
__device__ __forceinline__ void pinB(s8v (&b1)[16], s8v (&b2)[16]) {
#pragma unroll
    for (int kt = 0; kt < 16; ++kt) {
        asm volatile("" : "+v"(b1[kt]));
        asm volatile("" : "+v"(b2[kt]));
    }
}

// C[32 rows][cols 32w..32w+31] = (A1+A2) @ (B1+B2), 3-product, TWO acc chains
__device__ __forceinline__ void mfma_pass32(const char* A1s, const char* A2s,
                                            const s8v (&b1)[16], const s8v (&b2)[16],
                                            char* Cb, int w, int l) {
    f16v acc0, acc1;
#pragma unroll
    for (int i = 0; i < 16; ++i) { acc0[i] = 0.f; acc1[i] = 0.f; }
#pragma unroll
    for (int kt = 0; kt < 16; ++kt) {
        int off = aoff(l & 31, kt * 32 + (l >> 5) * 16);
        s8v a1 = *(const s8v*)(A1s + off);
        s8v a2 = *(const s8v*)(A2s + off);
        acc0 = __builtin_amdgcn_mfma_f32_32x32x16_bf16(a1, b1[kt], acc0, 0, 0, 0);
        acc1 = __builtin_amdgcn_mfma_f32_32x32x16_bf16(a2, b1[kt], acc1, 0, 0, 0);
        if (kt & 1) acc1 = __builtin_amdgcn_mfma_f32_32x32x16_bf16(a1, b2[kt], acc1, 0, 0, 0);
        else        acc0 = __builtin_amdgcn_mfma_f32_32x32x16_bf16(a1, b2[kt], acc0, 0, 0, 0);
    }
    const int col = 32 * w + (l & 31);
#pragma unroll
    for (int reg = 0; reg < 16; ++reg) {
        int row = (reg & 3) + 8 * (reg >> 2) + 4 * (l >> 5);
        *(float*)(Cb + coff(row, 4 * col)) = acc0[reg] + acc1[reg];
    }
}

// ---- K1: sentence encodings + ek = enc . keys^T ; one wave per (b,s) ----
__global__ __launch_bounds__(256)
void enc_ek(const int* __restrict__ prgrph,
            const unsigned char* __restrict__ pm8, const int* __restrict__ pm32,
            const float* __restrict__ keys, const float* __restrict__ emb,
            float* __restrict__ enc, float* __restrict__ ek,
            unsigned char* __restrict__ smask) {
    const int t = threadIdx.x, w = t >> 6, l = t & 63;
    int probe;
    { const unsigned char* p = pm8 + 4 * t; probe = (int)(p[1] | p[2] | p[3]); }
    const bool bytemode = (__syncthreads_or(probe) != 0);

    const int sid = blockIdx.x * 4 + w;            // (b,s) id, 0..B*Sc-1
    const int b = sid >> 6;

    int mv = 0;
    if (l < Lc) mv = bytemode ? (int)pm8[(size_t)sid * Lc + l] : pm32[(size_t)sid * Lc + l];
    unsigned long long bal = __ballot(mv != 0);
    const unsigned bits = (unsigned)(bal & 0xFFFFull);
    if (l == 0) smask[sid] = bits ? 1 : 0;

    const int* tb = prgrph + (size_t)sid * Lc;
    f4v acc = {0.f, 0.f, 0.f, 0.f};
#pragma unroll
    for (int i = 0; i < Lc; ++i) {
        int tok = tb[i];
        float m = (float)((bits >> i) & 1u);
        f4v ev = *(const f4v*)(emb + (size_t)tok * Dc + 4 * l);
        acc[0] += m * ev[0]; acc[1] += m * ev[1]; acc[2] += m * ev[2]; acc[3] += m * ev[3];
    }
    *(f4v*)(enc + (size_t)sid * Dc + 4 * l) = acc;

    const float* kb = keys + (size_t)b * Kc * Dc;
    float myek = 0.f;
#pragma unroll
    for (int k = 0; k < Kc; ++k) {
        f4v k4 = *(const f4v*)(kb + (size_t)k * Dc + 4 * l);
        float p = acc[0] * k4[0] + acc[1] * k4[1] + acc[2] * k4[2] + acc[3] * k4[3];
        p = wave_sum(p);
        if (l == k) myek = p;
    }
    if (l < Kc) ek[(size_t)sid * 32 + l] = myek;
}

// ---- K2: eW = enc @ W (one 32-sentence tile per block) ----
__global__ __launch_bounds__(512)
void ew_pass(const float* __restrict__ enc, const short* __restrict__ P,
             float* __restrict__ eW) {
    const int t = threadIdx.x, w = t >> 6, l = t & 63;
    const int b = blockIdx.x >> 1, pass = blockIdx.x & 1;
    __shared__ __align__(16) char lds[65536];
    char* A1s = lds; char* A2s = lds + 16384; char* Cb = lds + 32768;
    s8v b1[16], b2[16];
    loadB(P + 262144, P + 327680, w, l, b1, b2);
    const float* eb = enc + ((size_t)b * Sc + pass * 32) * Dc;
#pragma unroll
    for (int r = 0; r < 4; ++r) {
        int row = 4 * w + r;
        f4v ev = *(const f4v*)(eb + (size_t)row * Dc + 4 * l);
        store_split_row(A1s, A2s, row, l, ev[0], ev[1], ev[2], ev[3]);
    }
    __syncthreads();
    mfma_pass32(A1s, A2s, b1, b2, Cb, w, l);
    __syncthreads();
    float* ob = eW + ((size_t)b * Sc + pass * 32) * Dc;
#pragma unroll
    for (int r = 0; r < 4; ++r) {
        int row = 4 * w + r;
        f4v yv = *(const f4v*)(Cb + coff(row, 16 * l));
        *(f4v*)(ob + (size_t)row * Dc + 4 * l) = yv;
    }
}

// ---- K3: kv = keys @ V ----
__global__ __launch_bounds__(512)
void kv_pass(const float* __restrict__ keys, const short* __restrict__ P,
             float* __restrict__ kvp) {
    const int t = threadIdx.x, w = t >> 6, l = t & 63;
    const int b = blockIdx.x;
    __shared__ __align__(16) char lds[65536];
    char* A1s = lds; char* A2s = lds + 16384; char* Cb = lds + 32768;
    s8v b1[16], b2[16];
    loadB(P + 131072, P + 196608, w, l, b1, b2);
    const float* kb = keys + (size_t)b * Kc * Dc;
#pragma unroll
    for (int r = 0; r < 4; ++r) {
        int row = 4 * w + r;
        f4v k4 = (row < Kc) ? *(const f4v*)(kb + (size_t)row * Dc + 4 * l)
                            : (f4v){0.f, 0.f, 0.f, 0.f};
        store_split_row(A1s, A2s, row, l, k4[0], k4[1], k4[2], k4[3]);
    }
    __syncthreads();
    mfma_pass32(A1s, A2s, b1, b2, Cb, w, l);
    __syncthreads();
    float* ob = kvp + (size_t)b * 32 * Dc;
#pragma unroll
    for (int r = 0; r < 4; ++r) {
        int row = 4 * w + r;
        if (row < Kc) {
            f4v yv = *(const f4v*)(Cb + coff(row, 16 * l));
            *(f4v*)(ob + (size_t)row * Dc + 4 * l) = yv;
        }
    }
}

// ---- K4: the scan (deferred normalization; B pinned in VGPRs) ----
__global__ __launch_bounds__(512, 2)
void scan_k(const float* __restrict__ enc, const float* __restrict__ eW,
            const float* __restrict__ kvp, const float* __restrict__ ek,
            const unsigned char* __restrict__ smask, const short* __restrict__ P,
            float* __restrict__ out) {
    const int b = blockIdx.x, t = threadIdx.x;
    const int w = t >> 6, l = t & 63;

    __shared__ __align__(16) char lds[65536];
    char* A1s = lds; char* A2s = lds + 16384; char* Cb = lds + 32768;
    __shared__ unsigned char sm[Sc];

    if (t < Sc) sm[t] = smask[(size_t)b * Sc + t];
    // zero A planes (u = 0)
    {
        s8v z;
#pragma unroll
        for (int i = 0; i < 8; ++i) z[i] = 0;
        char* base = lds + t * 64;
#pragma unroll
        for (int i = 0; i < 4; ++i) *(s8v*)(base + 16 * i) = z;
    }

    s8v b1[16], b2[16];
    loadB(P, P + 65536, w, l, b1, b2);   // U planes -> 128 VGPR
    pinB(b1, b2);                        // keep them there (r6: compiler sank these)

    f4v kvr[4];
#pragma unroll
    for (int r = 0; r < 4; ++r) {
        int row = 4 * w + r;
        kvr[r] = (row < Kc) ? *(const f4v*)(kvp + ((size_t)b * 32 + row) * Dc + 4 * l)
                            : (f4v){0.f, 0.f, 0.f, 0.f};
    }
    f4v u[4];
#pragma unroll
    for (int r = 0; r < 4; ++r) u[r] = (f4v){0.f, 0.f, 0.f, 0.f};

    const float* eb  = enc + (size_t)b * Sc * Dc;
    const float* ewb = eW  + (size_t)b * Sc * Dc;
    const float* ekb = ek  + (size_t)b * Sc * 32;
    __syncthreads();

#pragma unroll 1
    for (int s = 0; s < Sc; ++s) {
        if (!sm[s]) continue;

        f4v e4  = *(const f4v*)(eb  + (size_t)s * Dc + 4 * l);
        f4v ew4 = *(const f4v*)(ewb + (size_t)s * Dc + 4 * l);
        float ekr[4];
#pragma unroll
        for (int r = 0; r < 4; ++r) {
            int row = 4 * w + r;
            ekr[r] = (row < Kc) ? ekb[(size_t)s * 32 + row] : 0.f;
        }

        mfma_pass32(A1s, A2s, b1, b2, Cb, w, l);   // y_raw = u_prev @ U

        // deferred finalize of u_prev (DPP reductions overlap MFMA drain):
        float rs[4], g[4];
#pragma unroll
        for (int r = 0; r < 4; ++r) {
            int row = 4 * w + r;
            if (row < Kc) {
                float ssl = u[r][0]*u[r][0] + u[r][1]*u[r][1] + u[r][2]*u[r][2] + u[r][3]*u[r][3];
                float ss = wave_sum(ssl);
                ss = fmaxf(ss, 1e-12f);
                float q = rsqrtf(ss);
                q = q * (1.5f - 0.5f * ss * q * q);     // Newton
                rs[r] = q;
                float eul = e4[0]*u[r][0] + e4[1]*u[r][1] + e4[2]*u[r][2] + e4[3]*u[r][3];
                float eu = wave_sum(eul);
                g[r] = 1.f / (1.f + __expf(-(rs[r] * eu + ekr[r])));
            }
        }
        __syncthreads();   // C ready

#pragma unroll
        for (int r = 0; r < 4; ++r) {
            int row = 4 * w + r;
            if (row >= Kc) continue;
            f4v yv = *(const f4v*)(Cb + coff(row, 16 * l));
            float t0 = fmaxf(rs[r]*yv[0] + kvr[r][0] + ew4[0], 0.f);
            float t1 = fmaxf(rs[r]*yv[1] + kvr[r][1] + ew4[1], 0.f);
            float t2 = fmaxf(rs[r]*yv[2] + kvr[r][2] + ew4[2], 0.f);
            float t3 = fmaxf(rs[r]*yv[3] + kvr[r][3] + ew4[3], 0.f);
            float u0 = rs[r]*u[r][0] + g[r]*t0;
            float u1 = rs[r]*u[r][1] + g[r]*t1;
            float u2 = rs[r]*u[r][2] + g[r]*t2;
            float u3 = rs[r]*u[r][3] + g[r]*t3;
            u[r][0]=u0; u[r][1]=u1; u[r][2]=u2; u[r][3]=u3;
            store_split_row(A1s, A2s, row, l, u0, u1, u2, u3);
        }
        __syncthreads();   // planes updated for next step
    }

    // epilogue: final normalize + write
    float* out_b = out + (size_t)b * (Kc * Dc);
#pragma unroll
    for (int r = 0; r < 4; ++r) {
        int row = 4 * w + r;
        if (row >= Kc) continue;
        float ssl = u[r][0]*u[r][0] + u[r][1]*u[r][1] + u[r][2]*u[r][2] + u[r][3]*u[r][3];
        float ss = wave_sum(ssl);
        ss = fmaxf(ss, 1e-12f);
        float q = rsqrtf(ss);
        q = q * (1.5f - 0.5f * ss * q * q);
        f4v o; o[0]=q*u[r][0]; o[1]=q*u[r][1]; o[2]=q*u[r][2]; o[3]=q*u[r][3];
        *(f4v*)(out_b + (size_t)row * Dc + 4 * l) = o;
    }
}

extern "C" void kernel_launch(void* const* d_in, const int* in_sizes, int n_in,
                              void* d_out, int out_size, void* d_ws, size_t ws_size,
                              hipStream_t stream) {
    const int*   prgrph = (const int*)d_in[0];
    const void*  pmask  = d_in[1];
    const float* keys   = (const float*)d_in[2];
    const float* emb    = (const float*)d_in[3];
    const float* U      = (const float*)d_in[4];
    const float* V      = (const float*)d_in[5];
    const float* W      = (const float*)d_in[6];

    const int B = in_sizes[2] / (Kc * Dc);   // keys is [B,K,D]

    char* ws = (char*)d_ws;
    short* P            = (short*)ws;                              // 768 KB
    float* enc          = (float*)(ws + 786432);                   // B*S*D f32 = 16.78 MB
    float* eW           = (float*)(ws + 786432 + 16777216);        // 16.78 MB
    float* kvp          = (float*)(ws + 786432 + 2*16777216);      // B*32*D f32 = 8.39 MB
    float* ekp          = (float*)(ws + 786432 + 2*16777216 + 8388608);  // B*S*32 = 2.10 MB
    unsigned char* smk  = (unsigned char*)(ws + 786432 + 2*16777216 + 8388608 + 2097152);

    pack32 <<<96, 256, 0, stream>>>(U, V, W, P);
    enc_ek <<<B * Sc / 4, 256, 0, stream>>>(prgrph, (const unsigned char*)pmask,
                                            (const int*)pmask, keys, emb, enc, ekp, smk);
    ew_pass<<<B * 2, 512, 0, stream>>>(enc, P, eW);
    kv_pass<<<B, 512, 0, stream>>>(keys, P, kvp);
    scan_k <<<B, 512, 0, stream>>>(enc, eW, kvp, ekp, smk, P, (float*)d_out);
}